// Round 1
// baseline (2548.798 us; speedup 1.0000x reference)
//
#include <hip/hip_runtime.h>
#include <math.h>

#define NB 512
#define NNODE 22
#define HH 128
#define HP 129          // padded LDS row stride (odd -> distinct banks across rows)
#define NEDGE 462       // 22*21 edges per graph
#define NLAYER 4
#define CHUNK 64
#define NCHUNK 8        // ceil(462/64)
#define SIG 0.168f

__device__ __forceinline__ float siluf(float v) { return v / (1.0f + __expf(-v)); }

__global__ __launch_bounds__(256, 2)
void scorenet_kernel(
    const float* __restrict__ xt, const float* __restrict__ tt,
    const float* __restrict__ atom_table, const float* __restrict__ bond_mask,
    const float* __restrict__ W_in, const float* __restrict__ b_in,
    const float* __restrict__ ew1, const float* __restrict__ eb1,
    const float* __restrict__ ew2, const float* __restrict__ eb2,
    const float* __restrict__ aw,  const float* __restrict__ ab,
    const float* __restrict__ cw1, const float* __restrict__ cb1,
    const float* __restrict__ cw2,
    const float* __restrict__ nw1, const float* __restrict__ nb1,
    const float* __restrict__ nw2, const float* __restrict__ nb2,
    const int* __restrict__ atom_types,
    float* __restrict__ out)
{
  const int g    = blockIdx.x;
  const int tid  = threadIdx.x;
  const int lane = tid & 63;
  const int wv   = tid >> 6;
  const int o_grp = lane & 15;   // lane owns outputs [o_grp*8, o_grp*8+8)
  const int e_grp = lane >> 4;   // lane owns edges  wv*16 + e_grp*4 + {0..3}
  const int ob    = o_grp * 8;

  __shared__ float sh_h[NNODE][HP];
  __shared__ float sh_agg[NNODE][HP];
  __shared__ float sh_x[NNODE][3];
  __shared__ float sh_xacc[NNODE][3];
  __shared__ float sh_d0[NEDGE];
  __shared__ float sh_bond[NEDGE];
  __shared__ __align__(16) float sh_w[32 * HH];   // weight staging (32 rows x 128)
  __shared__ float sh_m[CHUNK][HP];               // per-chunk edge message buffer
  __shared__ float sh_rad[CHUNK];
  __shared__ float sh_cd[3][CHUNK];
  __shared__ float sh_gp[CHUNK][4];
  __shared__ float sh_gate[CHUNK];
  __shared__ float sh_cmul[CHUNK];
  __shared__ float sh_awl[HH];
  __shared__ float sh_cw2l[HH];
  __shared__ float sh_tf[32];
  __shared__ float sh_scal[4];
  __shared__ float sh_mean[3];

  // ---------------- init ----------------
  if (tid == 0) {
    float tg = tt[g];
    sh_scal[0] = rsqrtf(tg * tg + SIG * SIG);  // c_in
    sh_scal[1] = tg;
  }
  __syncthreads();
  const float c_in = sh_scal[0];
  for (int idx = tid; idx < NNODE * 3; idx += 256)
    sh_x[idx / 3][idx % 3] = xt[(size_t)g * NNODE * 3 + idx] * c_in;
  if (tid < 32) {
    float u = __logf(sh_scal[1]) * 0.25f;
    int   q = tid & 15;
    float f = __expf((float)q * -0.5756462732485115f);  // exp(-ln(10000)*q/16)
    float a = u * f;
    sh_tf[tid] = (tid < 16) ? __sinf(a) : __cosf(a);
  }
  __syncthreads();
  // Tvec -> sh_m[0], per-atom-type vectors -> sh_m[1..4]
  for (int o = tid; o < HH; o += 256) {
    float s = b_in[o];
#pragma unroll 8
    for (int k = 0; k < 32; k++) s += sh_tf[k] * W_in[k * HH + o];
    sh_m[0][o] = s;
  }
  for (int idx = tid; idx < 4 * HH; idx += 256) {
    int a = idx >> 7, o = idx & 127;
    float s = 0.f;
#pragma unroll 8
    for (int k = 0; k < 32; k++) s += atom_table[a * 32 + k] * W_in[(32 + k) * HH + o];
    sh_m[1 + a][o] = s;
  }
  for (int e = tid; e < NEDGE; e += 256) {
    unsigned eu = e; int i = eu / 21; int r = eu - i * 21; int j = r + (r >= i);
    float dx = sh_x[i][0] - sh_x[j][0];
    float dy = sh_x[i][1] - sh_x[j][1];
    float dz = sh_x[i][2] - sh_x[j][2];
    sh_d0[e]   = dx * dx + dy * dy + dz * dz;
    sh_bond[e] = bond_mask[(size_t)g * NEDGE + e];
  }
  for (int idx = tid; idx < NNODE * 3; idx += 256) sh_xacc[idx / 3][idx % 3] = 0.f;
  for (int idx = tid; idx < NNODE * HH; idx += 256) sh_agg[idx >> 7][idx & 127] = 0.f;
  __syncthreads();
  for (int idx = tid; idx < NNODE * HH; idx += 256) {
    int n = idx >> 7, o = idx & 127;
    int at = atom_types[n];
    sh_h[n][o] = sh_m[0][o] + sh_m[1 + at][o];
  }
  __syncthreads();

  const float* hflat   = &sh_h[0][0];
  const float* aggflat = &sh_agg[0][0];
  const float* mflat   = &sh_m[0][0];

  auto stage = [&](const float* __restrict__ src, int nelem4) {
    __syncthreads();
    const float4* s4 = (const float4*)src;
    float4* d4 = (float4*)sh_w;
    for (int idx = tid; idx < nelem4; idx += 256) d4[idx] = s4[idx];
    __syncthreads();
  };

  auto initacc = [&](float (&a)[4][8], const float* __restrict__ bias) {
    float4 b0 = *(const float4*)&bias[ob];
    float4 b1 = *(const float4*)&bias[ob + 4];
#pragma unroll
    for (int j4 = 0; j4 < 4; j4++) {
      a[j4][0] = b0.x; a[j4][1] = b0.y; a[j4][2] = b0.z; a[j4][3] = b0.w;
      a[j4][4] = b1.x; a[j4][5] = b1.y; a[j4][6] = b1.z; a[j4][7] = b1.w;
    }
  };

  // 32-step K-slab GEMM: acc[4 edges][8 outs] += A[off[j]+k0+kk] * sh_w[kk][ob..ob+8)
  auto gemm32 = [&](float (&acc)[4][8], const float* __restrict__ base,
                    const int (&off)[4], int k0) {
#pragma unroll 4
    for (int kk = 0; kk < 32; kk++) {
      float4 wa = *(const float4*)&sh_w[kk * HH + ob];
      float4 wb = *(const float4*)&sh_w[kk * HH + ob + 4];
      float av[4];
#pragma unroll
      for (int j4 = 0; j4 < 4; j4++) av[j4] = base[off[j4] + k0 + kk];
#pragma unroll
      for (int j4 = 0; j4 < 4; j4++) {
        acc[j4][0] += av[j4] * wa.x; acc[j4][1] += av[j4] * wa.y;
        acc[j4][2] += av[j4] * wa.z; acc[j4][3] += av[j4] * wa.w;
        acc[j4][4] += av[j4] * wb.x; acc[j4][5] += av[j4] * wb.y;
        acc[j4][6] += av[j4] * wb.z; acc[j4][7] += av[j4] * wb.w;
      }
    }
  };

  // ---------------- layers ----------------
  for (int l = 0; l < NLAYER; l++) {
    const float* ew1l = ew1 + (size_t)l * 259 * HH;
    const float* eb1l = eb1 + l * HH;
    const float* ew2l = ew2 + (size_t)l * HH * HH;
    const float* eb2l = eb2 + l * HH;
    const float* cw1l = cw1 + (size_t)l * HH * HH;
    const float* cb1l = cb1 + l * HH;

    if (tid < HH) sh_awl[tid] = aw[l * HH + tid];
    else          sh_cw2l[tid - 128] = cw2[l * HH + (tid - 128)];
    __syncthreads();

    for (int ch = 0; ch < NCHUNK; ch++) {
      const int e0 = ch * CHUNK;
      // per-chunk geometry
      if (tid < CHUNK) {
        int e = e0 + tid;
        if (e < NEDGE) {
          unsigned eu = e; int i = eu / 21; int r = eu - i * 21; int j = r + (r >= i);
          float dx = sh_x[i][0] - sh_x[j][0];
          float dy = sh_x[i][1] - sh_x[j][1];
          float dz = sh_x[i][2] - sh_x[j][2];
          float rad = dx * dx + dy * dy + dz * dz;
          float inv = 1.0f / (sqrtf(rad) + 1.0f);
          sh_rad[tid] = rad;
          sh_cd[0][tid] = dx * inv; sh_cd[1][tid] = dy * inv; sh_cd[2][tid] = dz * inv;
        } else {
          sh_rad[tid] = 0.f;
          sh_cd[0][tid] = 0.f; sh_cd[1][tid] = 0.f; sh_cd[2][tid] = 0.f;
        }
      }
      __syncthreads();

      int off_i[4], off_j[4], my_le[4], moff[4];
      float radr[4], d0r[4], bndr[4];
#pragma unroll
      for (int j4 = 0; j4 < 4; j4++) {
        int le = wv * 16 + e_grp * 4 + j4;
        int e  = e0 + le;
        my_le[j4] = le;
        moff[j4]  = le * HP;
        radr[j4]  = sh_rad[le];
        if (e < NEDGE) {
          unsigned eu = e; int i = eu / 21; int r = eu - i * 21; int j = r + (r >= i);
          off_i[j4] = i * HP; off_j[j4] = j * HP;
          d0r[j4] = sh_d0[e]; bndr[j4] = sh_bond[e];
        } else {
          off_i[j4] = 0; off_j[j4] = 0; d0r[j4] = 0.f; bndr[j4] = 0.f;
        }
      }

      // ---- edge MLP layer 1: K = 259 = 128(h_i) + 128(h_j) + 3(rad,d0,bond) ----
      float acc[4][8];
      initacc(acc, eb1l);
      for (int kc = 0; kc < 128; kc += 32) { stage(ew1l + kc * HH, 1024);        gemm32(acc, hflat, off_i, kc); }
      for (int kc = 0; kc < 128; kc += 32) { stage(ew1l + (128 + kc) * HH, 1024); gemm32(acc, hflat, off_j, kc); }
      stage(ew1l + 256 * HH, 3 * HH / 4);
      {
#pragma unroll
        for (int kk = 0; kk < 3; kk++) {
          float4 wa = *(const float4*)&sh_w[kk * HH + ob];
          float4 wb = *(const float4*)&sh_w[kk * HH + ob + 4];
          float av[4];
#pragma unroll
          for (int j4 = 0; j4 < 4; j4++)
            av[j4] = (kk == 0) ? radr[j4] : ((kk == 1) ? d0r[j4] : bndr[j4]);
#pragma unroll
          for (int j4 = 0; j4 < 4; j4++) {
            acc[j4][0] += av[j4] * wa.x; acc[j4][1] += av[j4] * wa.y;
            acc[j4][2] += av[j4] * wa.z; acc[j4][3] += av[j4] * wa.w;
            acc[j4][4] += av[j4] * wb.x; acc[j4][5] += av[j4] * wb.y;
            acc[j4][6] += av[j4] * wb.z; acc[j4][7] += av[j4] * wb.w;
          }
        }
      }
#pragma unroll
      for (int j4 = 0; j4 < 4; j4++)
#pragma unroll
        for (int c8 = 0; c8 < 8; c8++)
          sh_m[my_le[j4]][ob + c8] = siluf(acc[j4][c8]);

      // ---- edge MLP layer 2: K = 128 ----
      float acc2[4][8];
      initacc(acc2, eb2l);
      for (int kc = 0; kc < 128; kc += 32) { stage(ew2l + kc * HH, 1024); gemm32(acc2, mflat, moff, kc); }
#pragma unroll
      for (int j4 = 0; j4 < 4; j4++)
#pragma unroll
        for (int c8 = 0; c8 < 8; c8++)
          sh_m[my_le[j4]][ob + c8] = siluf(acc2[j4][c8]);
      __syncthreads();

      // ---- attention gate ----
      {
        int e = tid & 63, p = tid >> 6;
        float s = 0.f;
        int k0 = p * 32;
#pragma unroll 8
        for (int k = 0; k < 32; k++) s += sh_m[e][k0 + k] * sh_awl[k0 + k];
        sh_gp[e][p] = s;
      }
      __syncthreads();
      if (tid < CHUNK) {
        float gs = sh_gp[tid][0] + sh_gp[tid][1] + sh_gp[tid][2] + sh_gp[tid][3] + ab[l];
        sh_gate[tid] = 1.0f / (1.0f + __expf(-gs));
      }
      __syncthreads();
      for (int idx = tid; idx < CHUNK * HH; idx += 256) {
        int e = idx >> 7, o = idx & 127;
        sh_m[e][o] *= sh_gate[e];
      }
      __syncthreads();

      // ---- agg: segment_sum(m, row) (edges row-sorted -> per-row plain sum) ----
      int elast = (e0 + CHUNK < NEDGE ? e0 + CHUNK : NEDGE) - 1;
      int i_lo = e0 / 21, i_hi = elast / 21;
      int nrows = i_hi - i_lo + 1;
      for (int idx = tid; idx < nrows * HH; idx += 256) {
        int i = i_lo + (idx >> 7), o = idx & 127;
        int es = i * 21; if (es < e0) es = e0;
        int ee = i * 21 + 21;
        if (ee > e0 + CHUNK) ee = e0 + CHUNK;
        if (ee > NEDGE) ee = NEDGE;
        float s = 0.f;
        for (int e = es; e < ee; e++) s += sh_m[e - e0][o];
        sh_agg[i][o] += s;
      }

      // ---- coord head: K = 128 on gated m, then dot with cw2 ----
      float acc3[4][8];
      initacc(acc3, cb1l);
      for (int kc = 0; kc < 128; kc += 32) { stage(cw1l + kc * HH, 1024); gemm32(acc3, mflat, moff, kc); }
      {
        float csj[4];
#pragma unroll
        for (int j4 = 0; j4 < 4; j4++) {
          float s = 0.f;
#pragma unroll
          for (int c8 = 0; c8 < 8; c8++) s += siluf(acc3[j4][c8]) * sh_cw2l[ob + c8];
          csj[j4] = s;
        }
#pragma unroll
        for (int j4 = 0; j4 < 4; j4++) {
          csj[j4] += __shfl_xor(csj[j4], 1, 64);
          csj[j4] += __shfl_xor(csj[j4], 2, 64);
          csj[j4] += __shfl_xor(csj[j4], 4, 64);
          csj[j4] += __shfl_xor(csj[j4], 8, 64);
        }
        if (o_grp == 0) {
#pragma unroll
          for (int j4 = 0; j4 < 4; j4++) sh_cmul[my_le[j4]] = csj[j4];
        }
      }
      __syncthreads();

      // ---- x translation accumulate ----
      for (int idx = tid; idx < nrows * 3; idx += 256) {
        int i = i_lo + idx / 3, d = idx % 3;
        int es = i * 21; if (es < e0) es = e0;
        int ee = i * 21 + 21;
        if (ee > e0 + CHUNK) ee = e0 + CHUNK;
        if (ee > NEDGE) ee = NEDGE;
        float s = 0.f;
        for (int e = es; e < ee; e++) s += sh_cd[d][e - e0] * sh_cmul[e - e0];
        sh_xacc[i][d] += s;
      }
      __syncthreads();
    } // chunks

    // ---- node MLP: h += MLP(concat(h, agg)) ----
    {
      const float* nw1l = nw1 + (size_t)l * 256 * HH;
      const float* nb1l = nb1 + l * HH;
      const float* nw2l = nw2 + (size_t)l * HH * HH;
      const float* nb2l = nb2 + l * HH;
      int le0 = wv * 16 + e_grp * 4;
      int noff[4], moff[4];
#pragma unroll
      for (int j4 = 0; j4 < 4; j4++) {
        int le = le0 + j4;
        noff[j4] = (le < NNODE ? le : 0) * HP;
        moff[j4] = le * HP;
      }
      float a1[4][8];
      initacc(a1, nb1l);
      for (int kc = 0; kc < 128; kc += 32) { stage(nw1l + kc * HH, 1024);         gemm32(a1, hflat,   noff, kc); }
      for (int kc = 0; kc < 128; kc += 32) { stage(nw1l + (128 + kc) * HH, 1024); gemm32(a1, aggflat, noff, kc); }
#pragma unroll
      for (int j4 = 0; j4 < 4; j4++)
#pragma unroll
        for (int c8 = 0; c8 < 8; c8++)
          sh_m[le0 + j4][ob + c8] = siluf(a1[j4][c8]);
      float a2[4][8];
      initacc(a2, nb2l);
      for (int kc = 0; kc < 128; kc += 32) { stage(nw2l + kc * HH, 1024); gemm32(a2, mflat, moff, kc); }
#pragma unroll
      for (int j4 = 0; j4 < 4; j4++) {
        if (le0 + j4 < NNODE) {
#pragma unroll
          for (int c8 = 0; c8 < 8; c8++) sh_h[le0 + j4][ob + c8] += a2[j4][c8];
        }
      }
    }
    __syncthreads();
    // x += xacc; reset accumulators
    for (int idx = tid; idx < NNODE * 3; idx += 256) {
      int n = idx / 3, d = idx % 3;
      sh_x[n][d] += sh_xacc[n][d];
      sh_xacc[n][d] = 0.f;
    }
    for (int idx = tid; idx < NNODE * HH; idx += 256) sh_agg[idx >> 7][idx & 127] = 0.f;
    __syncthreads();
  } // layers

  // ---------------- epilogue ----------------
  if (tid < 3) {
    float s = 0.f;
    for (int n = 0; n < NNODE; n++) s += sh_x[n][tid];
    sh_mean[tid] = s * (1.0f / NNODE);
  }
  __syncthreads();
  {
    float tg = sh_scal[1];
    float den = tg * tg + SIG * SIG;
    float c_skip = (SIG * SIG) / den;
    float c_out  = tg * SIG * rsqrtf(den);
    for (int idx = tid; idx < NNODE * 3; idx += 256) {
      int n = idx / 3, d = idx % 3;
      out[(size_t)g * NNODE * 3 + idx] =
          xt[(size_t)g * NNODE * 3 + idx] * c_skip + (sh_x[n][d] - sh_mean[d]) * c_out;
    }
  }
}

extern "C" void kernel_launch(void* const* d_in, const int* in_sizes, int n_in,
                              void* d_out, int out_size, void* d_ws, size_t ws_size,
                              hipStream_t stream) {
  const float* xt         = (const float*)d_in[0];
  const float* t          = (const float*)d_in[1];
  const float* atom_table = (const float*)d_in[2];
  const float* bond_mask  = (const float*)d_in[3];
  const float* W_in       = (const float*)d_in[4];
  const float* b_in       = (const float*)d_in[5];
  const float* ew1        = (const float*)d_in[6];
  const float* eb1        = (const float*)d_in[7];
  const float* ew2        = (const float*)d_in[8];
  const float* eb2        = (const float*)d_in[9];
  const float* aw         = (const float*)d_in[10];
  const float* ab         = (const float*)d_in[11];
  const float* cw1        = (const float*)d_in[12];
  const float* cb1        = (const float*)d_in[13];
  const float* cw2        = (const float*)d_in[14];
  const float* nw1        = (const float*)d_in[15];
  const float* nb1        = (const float*)d_in[16];
  const float* nw2        = (const float*)d_in[17];
  const float* nb2        = (const float*)d_in[18];
  // d_in[19] = row, d_in[20] = col: edge structure is regenerated analytically in-kernel
  const int* atom_types   = (const int*)d_in[21];

  scorenet_kernel<<<NB, 256, 0, stream>>>(
      xt, t, atom_table, bond_mask, W_in, b_in,
      ew1, eb1, ew2, eb2, aw, ab, cw1, cb1, cw2,
      nw1, nb1, nw2, nb2, atom_types, (float*)d_out);
}

// Round 3
// 1087.445 us; speedup vs baseline: 2.3438x; 2.3438x over previous
//
#include <hip/hip_runtime.h>
#include <math.h>

#define NB 512
#define NNODE 22
#define HH 128
#define NEDGE 462
#define NLAYER 4
#define CHUNK 64
#define NCHUNK 8
#define SIG 0.168f

#define ASTR 136      // A-plane row stride (ushort), 272B (16B-aligned rows)
#define NSTR 264      // A-plane row stride for node concat (K=256), 528B
#define BSTR 72       // B-plane row stride (ushort), 144B
#define SLW (128*72)  // one weight plane in ushorts (= 9216; 18432 B)
#define LSLICES 14    // slices/layer: ew1:0-3, ew2:4-5, cw1:6-7, nw1:8-11, nw2:12-13

typedef __attribute__((ext_vector_type(8))) short short8;
typedef __attribute__((ext_vector_type(4))) float f32x4;

#define MFMA_BF16 __builtin_amdgcn_mfma_f32_16x16x32_bf16

__device__ __forceinline__ float siluf(float v) { return v / (1.0f + __expf(-v)); }

__device__ __forceinline__ unsigned short f2bf(float x) {
  union { float f; unsigned u; } v; v.f = x;
  unsigned r = v.u + 0x7FFFu + ((v.u >> 16) & 1u);
  return (unsigned short)(r >> 16);
}
__device__ __forceinline__ float bf2f(unsigned short h) {
  union { unsigned u; float f; } v; v.u = ((unsigned)h) << 16; return v.f;
}
// split fp32 -> (hi, lo) bf16 pair: hi+lo carries ~16 mantissa bits
__device__ __forceinline__ void splitbf(float x, unsigned short& hi, unsigned short& lo) {
  hi = f2bf(x);
  lo = f2bf(x - bf2f(hi));
}

// ---------------- prep: fp32 weights -> (hi,lo) bf16 planes, transposed [n][k] ----------------
__global__ void prep_weights(const float* __restrict__ ew1, const float* __restrict__ ew2,
                             const float* __restrict__ cw1, const float* __restrict__ nw1,
                             const float* __restrict__ nw2, unsigned short* __restrict__ ws)
{
  int idx = blockIdx.x * 256 + threadIdx.x;      // total = 4*14*128*72 = 516096
  if (idx >= 4 * LSLICES * 128 * 72) return;
  int kk = idx % 72; int rest = idx / 72;
  int n = rest % 128; rest /= 128;
  int sl = rest % LSLICES; int l = rest / LSLICES;
  float val = 0.f;
  if (kk < 64) {
    if (sl < 4)       val = ew1[((size_t)l * 259 + sl * 64 + kk) * HH + n];
    else if (sl < 6)  val = ew2[((size_t)l * 128 + (sl - 4) * 64 + kk) * HH + n];
    else if (sl < 8)  val = cw1[((size_t)l * 128 + (sl - 6) * 64 + kk) * HH + n];
    else if (sl < 12) val = nw1[((size_t)l * 256 + (sl - 8) * 64 + kk) * HH + n];
    else              val = nw2[((size_t)l * 128 + (sl - 12) * 64 + kk) * HH + n];
  }
  unsigned short hi, lo; splitbf(val, hi, lo);
  size_t base = ((size_t)(l * LSLICES + sl) * 2) * SLW + n * BSTR + kk;
  ws[base]       = hi;
  ws[base + SLW] = lo;
}

// ---------------- main ----------------
__global__ __launch_bounds__(256, 1)
void scorenet_kernel(
    const float* __restrict__ xt, const float* __restrict__ tt,
    const float* __restrict__ atom_table, const float* __restrict__ bond_mask,
    const float* __restrict__ W_in, const float* __restrict__ b_in,
    const float* __restrict__ ew1, const float* __restrict__ eb1,
    const float* __restrict__ eb2,
    const float* __restrict__ aw,  const float* __restrict__ ab,
    const float* __restrict__ cb1, const float* __restrict__ cw2,
    const float* __restrict__ nb1, const float* __restrict__ nb2,
    const int* __restrict__ atom_types,
    const unsigned short* __restrict__ ws,
    float* __restrict__ out)
{
  const int g    = blockIdx.x;
  const int tid  = threadIdx.x;
  const int lane = tid & 63;
  const int wv   = tid >> 6;
  const int ml   = lane & 15;   // MFMA: A row-in-tile / B col-in-tile / C col
  const int q    = lane >> 4;   // MFMA quad: A/B k = q*8+j ; C rows q*4+r

  __shared__ unsigned short sh_B[2 * 128 * BSTR];    // 36864 B: [hi 9216][lo 9216]
  __shared__ unsigned short sh_Ah[CHUNK * ASTR];     // 17408 B  A hi plane
  __shared__ unsigned short sh_Al[CHUNK * ASTR];     // 17408 B  A lo plane
  __shared__ float sh_Phi[2][NNODE * HH];            // 22528 B  fp32 per-node ew1 partials
  __shared__ float sh_h[NNODE * HH];                 // 11264 B
  __shared__ float sh_agg[NNODE * HH];               // 11264 B
  __shared__ float sh_tail[8 * HH];                  // 4096 B: ew1 r256,257,258; eb1; eb2; cb1; nb1; nb2
  __shared__ float sh_awl[HH], sh_cw2l[HH];
  __shared__ float sh_x[NNODE][3], sh_xacc[NNODE][3];
  __shared__ float sh_d0[NEDGE], sh_bond[NEDGE];
  __shared__ float sh_rad[CHUNK], sh_cd[3][CHUNK], sh_gate[CHUNK], sh_cmul[CHUNK];
  __shared__ float sh_tf[32], sh_scal[2], sh_mean[3];

  // stage one (hi,lo) weight plane pair: 36864 bytes
  auto stageB = [&](const unsigned short* src) {
    __syncthreads();
    const char* s8 = (const char*)src;
    char* dbase = (char*)&sh_B[0];
    for (int base = wv * 1024; base < 36864; base += 4096) {
      __builtin_amdgcn_global_load_lds(
          (const __attribute__((address_space(1))) unsigned int*)(s8 + base + lane * 16),
          (__attribute__((address_space(3))) unsigned int*)(dbase + base),
          16, 0, 0);
    }
    __syncthreads();
  };

  // ---------------- init ----------------
  if (tid == 0) {
    float tg = tt[g];
    sh_scal[0] = rsqrtf(tg * tg + SIG * SIG);
    sh_scal[1] = tg;
  }
  __syncthreads();
  const float c_in = sh_scal[0];
  for (int idx = tid; idx < NNODE * 3; idx += 256) {
    sh_x[idx / 3][idx % 3] = xt[(size_t)g * NNODE * 3 + idx] * c_in;
    sh_xacc[idx / 3][idx % 3] = 0.f;
  }
  if (tid < 32) {
    float u = __logf(sh_scal[1]) * 0.25f;
    int   qq = tid & 15;
    float f = __expf((float)qq * -0.5756462732485115f);
    float a = u * f;
    sh_tf[tid] = (tid < 16) ? __sinf(a) : __cosf(a);
  }
  __syncthreads();
  // Tvec -> sh_agg row 0, atom-type vecs -> rows 1..4 (scratch)
  for (int o = tid; o < HH; o += 256) {
    float s = b_in[o];
#pragma unroll 8
    for (int k = 0; k < 32; k++) s += sh_tf[k] * W_in[k * HH + o];
    sh_agg[o] = s;
  }
  for (int idx = tid; idx < 4 * HH; idx += 256) {
    int a = idx >> 7, o = idx & 127;
    float s = 0.f;
#pragma unroll 8
    for (int k = 0; k < 32; k++) s += atom_table[a * 32 + k] * W_in[(32 + k) * HH + o];
    sh_agg[(1 + a) * HH + o] = s;
  }
  for (int e = tid; e < NEDGE; e += 256) {
    int i = e / 21; int r = e - i * 21; int jn = r + (r >= i);
    float dx = sh_x[i][0] - sh_x[jn][0];
    float dy = sh_x[i][1] - sh_x[jn][1];
    float dz = sh_x[i][2] - sh_x[jn][2];
    sh_d0[e]   = dx * dx + dy * dy + dz * dz;
    sh_bond[e] = bond_mask[(size_t)g * NEDGE + e];
  }
  __syncthreads();
  for (int idx = tid; idx < NNODE * HH; idx += 256) {
    int n = idx >> 7, o = idx & 127;
    int at = atom_types[n];
    sh_h[idx] = sh_agg[o] + sh_agg[(1 + at) * HH + o];
  }
  __syncthreads();
  for (int idx = tid; idx < NNODE * HH; idx += 256) sh_agg[idx] = 0.f;

  // ---------------- layers ----------------
  for (int l = 0; l < NLAYER; l++) {
    const unsigned short* wsL = ws + (size_t)l * LSLICES * 2 * SLW;
    const float abl = ab[l];

    // per-layer vectors -> LDS (fp32, never rounded)
    for (int idx = tid; idx < 8 * HH; idx += 256) {
      int rsel = idx >> 7, n = idx & 127;
      float v;
      switch (rsel) {
        case 0: v = ew1[((size_t)l * 259 + 256) * HH + n]; break;
        case 1: v = ew1[((size_t)l * 259 + 257) * HH + n]; break;
        case 2: v = ew1[((size_t)l * 259 + 258) * HH + n]; break;
        case 3: v = eb1[l * HH + n]; break;
        case 4: v = eb2[l * HH + n]; break;
        case 5: v = cb1[l * HH + n]; break;
        case 6: v = nb1[l * HH + n]; break;
        default: v = nb2[l * HH + n]; break;
      }
      sh_tail[idx] = v;
    }
    if (tid < HH) sh_awl[tid] = aw[l * HH + tid];
    else if (tid < 2 * HH) sh_cw2l[tid - HH] = cw2[l * HH + (tid - HH)];
    __syncthreads();

    // ---- h -> split bf16 A planes (stride ASTR, rows 0..21) ----
    for (int idx = tid; idx < NNODE * 16; idx += 256) {
      int nd = idx >> 4, nb = (idx & 15) * 8;
      const float* hp = &sh_h[nd * HH + nb];
      union { short8 v; unsigned short s[8]; } oh, ol;
#pragma unroll
      for (int jj = 0; jj < 8; jj++) { unsigned short hi, lo; splitbf(hp[jj], hi, lo); oh.s[jj] = hi; ol.s[jj] = lo; }
      *(short8*)&sh_Ah[nd * ASTR + nb] = oh.v;
      *(short8*)&sh_Al[nd * ASTR + nb] = ol.v;
    }

    // ---- Phi GEMMs: Phi[side] = h @ ew1[side*128 : +128]  (fp32 out) ----
    {
      int mt = wv & 1, nh = wv >> 1;
      for (int side = 0; side < 2; side++) {
        f32x4 zf = {0.f, 0.f, 0.f, 0.f};
        f32x4 accP[4]; accP[0] = zf; accP[1] = zf; accP[2] = zf; accP[3] = zf;
        for (int s2 = 0; s2 < 2; s2++) {
          stageB(wsL + (side * 2 + s2) * 2 * SLW);
          for (int sb = 0; sb < 2; sb++) {
            int ak = (mt * 16 + ml) * ASTR + s2 * 64 + sb * 32 + q * 8;
            short8 ah = *(const short8*)&sh_Ah[ak];
            short8 al = *(const short8*)&sh_Al[ak];
#pragma unroll
            for (int t = 0; t < 4; t++) {
              int bi = ((nh * 4 + t) * 16 + ml) * BSTR + sb * 32 + q * 8;
              short8 bh = *(const short8*)&sh_B[bi];
              short8 bl = *(const short8*)&sh_B[9216 + bi];
              accP[t] = MFMA_BF16(ah, bh, accP[t], 0, 0, 0);
              accP[t] = MFMA_BF16(ah, bl, accP[t], 0, 0, 0);
              accP[t] = MFMA_BF16(al, bh, accP[t], 0, 0, 0);
            }
          }
        }
#pragma unroll
        for (int t = 0; t < 4; t++) {
          int col = (nh * 4 + t) * 16 + ml;
#pragma unroll
          for (int r = 0; r < 4; r++) {
            int row = mt * 16 + q * 4 + r;
            if (row < NNODE) sh_Phi[side][row * HH + col] = accP[t][r];
          }
        }
      }
    }

    // ---- edge chunks ----
    for (int ch = 0; ch < NCHUNK; ch++) {
      const int e0 = ch * CHUNK;
      if (tid < CHUNK) {
        int e = e0 + tid;
        if (e < NEDGE) {
          int i = e / 21; int r = e - i * 21; int jn = r + (r >= i);
          float dx = sh_x[i][0] - sh_x[jn][0];
          float dy = sh_x[i][1] - sh_x[jn][1];
          float dz = sh_x[i][2] - sh_x[jn][2];
          float rad = dx * dx + dy * dy + dz * dz;
          float inv = 1.0f / (sqrtf(rad) + 1.0f);
          sh_rad[tid] = rad;
          sh_cd[0][tid] = dx * inv; sh_cd[1][tid] = dy * inv; sh_cd[2][tid] = dz * inv;
        } else {
          sh_rad[tid] = 0.f;
          sh_cd[0][tid] = 0.f; sh_cd[1][tid] = 0.f; sh_cd[2][tid] = 0.f;
        }
      }
      __syncthreads();

      // ---- prologue: m1 = silu(Phi_i + Phi_j + rad*w256 + d0*w257 + bond*w258 + eb1) ----
      {
        int nb = (tid & 15) * 8, eb_ = tid >> 4;
        for (int j4 = 0; j4 < 4; j4++) {
          int el = eb_ + 16 * j4; int e = e0 + el;
          union { short8 v; unsigned short s[8]; } oh, ol;
          if (e < NEDGE) {
            int i = e / 21; int r = e - i * 21; int jn = r + (r >= i);
            float rad = sh_rad[el], d0v = sh_d0[e], bnd = sh_bond[e];
            const float* pi = &sh_Phi[0][i * HH + nb];
            const float* pj = &sh_Phi[1][jn * HH + nb];
#pragma unroll
            for (int jj = 0; jj < 8; jj++) {
              float v = pi[jj] + pj[jj] +
                        rad * sh_tail[nb + jj] + d0v * sh_tail[128 + nb + jj] +
                        bnd * sh_tail[256 + nb + jj] + sh_tail[384 + nb + jj];
              unsigned short hi, lo; splitbf(siluf(v), hi, lo);
              oh.s[jj] = hi; ol.s[jj] = lo;
            }
          } else {
#pragma unroll
            for (int jj = 0; jj < 8; jj++) { oh.s[jj] = 0; ol.s[jj] = 0; }
          }
          *(short8*)&sh_Ah[el * ASTR + nb] = oh.v;
          *(short8*)&sh_Al[el * ASTR + nb] = ol.v;
        }
      }
      __syncthreads();

      // ---- ew2 GEMM: m2 = silu(m1 @ ew2 + eb2), wave = M-tile, 8 N-tiles ----
      f32x4 zf = {0.f, 0.f, 0.f, 0.f};
      f32x4 acc2[8];
#pragma unroll
      for (int t = 0; t < 8; t++) acc2[t] = zf;
      for (int s = 0; s < 2; s++) {
        stageB(wsL + (4 + s) * 2 * SLW);
        for (int sb = 0; sb < 2; sb++) {
          int ak = (wv * 16 + ml) * ASTR + s * 64 + sb * 32 + q * 8;
          short8 ah = *(const short8*)&sh_Ah[ak];
          short8 al = *(const short8*)&sh_Al[ak];
#pragma unroll
          for (int t = 0; t < 8; t++) {
            int bi = (t * 16 + ml) * BSTR + sb * 32 + q * 8;
            short8 bh = *(const short8*)&sh_B[bi];
            short8 bl = *(const short8*)&sh_B[9216 + bi];
            acc2[t] = MFMA_BF16(ah, bh, acc2[t], 0, 0, 0);
            acc2[t] = MFMA_BF16(ah, bl, acc2[t], 0, 0, 0);
            acc2[t] = MFMA_BF16(al, bh, acc2[t], 0, 0, 0);
          }
        }
      }
      {
        float gpr[4] = {0.f, 0.f, 0.f, 0.f};
#pragma unroll
        for (int t = 0; t < 8; t++) {
          int col = t * 16 + ml;
          float eb2c = sh_tail[512 + col], awc = sh_awl[col];
#pragma unroll
          for (int r = 0; r < 4; r++) {
            float v = siluf(acc2[t][r] + eb2c);
            unsigned short hi, lo; splitbf(v, hi, lo);
            int ai = (wv * 16 + q * 4 + r) * ASTR + col;
            sh_Ah[ai] = hi; sh_Al[ai] = lo;     // in-place m2 (wave-local rows)
            gpr[r] += v * awc;
          }
        }
#pragma unroll
        for (int m = 1; m < 16; m <<= 1)
#pragma unroll
          for (int r = 0; r < 4; r++) gpr[r] += __shfl_xor(gpr[r], m, 64);
        if (ml == 0) {
#pragma unroll
          for (int r = 0; r < 4; r++)
            sh_gate[wv * 16 + q * 4 + r] = 1.0f / (1.0f + __expf(-(gpr[r] + abl)));
        }
      }
      __syncthreads();

      // ---- agg += sum_e gate[e]*m2[e][:] (row-sorted segments) ----
      int elast = ((e0 + CHUNK < NEDGE) ? e0 + CHUNK : NEDGE) - 1;
      int i_lo = e0 / 21, i_hi = elast / 21;
      int nrows = i_hi - i_lo + 1;
      for (int idx = tid; idx < nrows * 16; idx += 256) {
        int i = i_lo + (idx >> 4), nb = (idx & 15) * 8;
        int es = i * 21; if (es < e0) es = e0;
        int ee = i * 21 + 21;
        if (ee > e0 + CHUNK) ee = e0 + CHUNK;
        if (ee > NEDGE) ee = NEDGE;
        float* ap = &sh_agg[i * HH + nb];
        float a8[8];
#pragma unroll
        for (int jj = 0; jj < 8; jj++) a8[jj] = ap[jj];
        for (int e = es; e < ee; e++) {
          float gg = sh_gate[e - e0];
          union { short8 v; unsigned short s[8]; } uh, ul;
          uh.v = *(const short8*)&sh_Ah[(e - e0) * ASTR + nb];
          ul.v = *(const short8*)&sh_Al[(e - e0) * ASTR + nb];
#pragma unroll
          for (int jj = 0; jj < 8; jj++) a8[jj] += gg * (bf2f(uh.s[jj]) + bf2f(ul.s[jj]));
        }
#pragma unroll
        for (int jj = 0; jj < 8; jj++) ap[jj] = a8[jj];
      }

      // ---- cw1 GEMM on (ungated) m2; gate folded into epilogue (linear) ----
      f32x4 acc3[8];
#pragma unroll
      for (int t = 0; t < 8; t++) acc3[t] = zf;
      for (int s = 0; s < 2; s++) {
        stageB(wsL + (6 + s) * 2 * SLW);
        for (int sb = 0; sb < 2; sb++) {
          int ak = (wv * 16 + ml) * ASTR + s * 64 + sb * 32 + q * 8;
          short8 ah = *(const short8*)&sh_Ah[ak];
          short8 al = *(const short8*)&sh_Al[ak];
#pragma unroll
          for (int t = 0; t < 8; t++) {
            int bi = (t * 16 + ml) * BSTR + sb * 32 + q * 8;
            short8 bh = *(const short8*)&sh_B[bi];
            short8 bl = *(const short8*)&sh_B[9216 + bi];
            acc3[t] = MFMA_BF16(ah, bh, acc3[t], 0, 0, 0);
            acc3[t] = MFMA_BF16(ah, bl, acc3[t], 0, 0, 0);
            acc3[t] = MFMA_BF16(al, bh, acc3[t], 0, 0, 0);
          }
        }
      }
      {
        float g4[4];
#pragma unroll
        for (int r = 0; r < 4; r++) g4[r] = sh_gate[wv * 16 + q * 4 + r];
        float cs[4] = {0.f, 0.f, 0.f, 0.f};
#pragma unroll
        for (int t = 0; t < 8; t++) {
          int col = t * 16 + ml;
          float cb1c = sh_tail[640 + col], cwc = sh_cw2l[col];
#pragma unroll
          for (int r = 0; r < 4; r++) {
            float v = siluf(g4[r] * acc3[t][r] + cb1c);
            cs[r] += v * cwc;
          }
        }
#pragma unroll
        for (int m = 1; m < 16; m <<= 1)
#pragma unroll
          for (int r = 0; r < 4; r++) cs[r] += __shfl_xor(cs[r], m, 64);
        if (ml == 0) {
#pragma unroll
          for (int r = 0; r < 4; r++) sh_cmul[wv * 16 + q * 4 + r] = cs[r];
        }
      }
      __syncthreads();

      // ---- x translation accumulate ----
      for (int idx = tid; idx < nrows * 3; idx += 256) {
        int i = i_lo + idx / 3, d = idx % 3;
        int es = i * 21; if (es < e0) es = e0;
        int ee = i * 21 + 21;
        if (ee > e0 + CHUNK) ee = e0 + CHUNK;
        if (ee > NEDGE) ee = NEDGE;
        float s = 0.f;
        for (int e = es; e < ee; e++) s += sh_cd[d][e - e0] * sh_cmul[e - e0];
        sh_xacc[i][d] += s;
      }
      __syncthreads();
    } // chunks

    // ---- node MLP ----
    {
      // [h | agg] -> split bf16 A planes (stride NSTR)
      for (int idx = tid; idx < NNODE * 32; idx += 256) {
        int nd = idx >> 5, kb = (idx & 31) * 8;
        const float* src = (kb < 128) ? &sh_h[nd * HH + kb] : &sh_agg[nd * HH + (kb - 128)];
        union { short8 v; unsigned short s[8]; } oh, ol;
#pragma unroll
        for (int jj = 0; jj < 8; jj++) { unsigned short hi, lo; splitbf(src[jj], hi, lo); oh.s[jj] = hi; ol.s[jj] = lo; }
        *(short8*)&sh_Ah[nd * NSTR + kb] = oh.v;
        *(short8*)&sh_Al[nd * NSTR + kb] = ol.v;
      }
      int mt = wv & 1, nh = wv >> 1;
      f32x4 zf = {0.f, 0.f, 0.f, 0.f};
      f32x4 n1[4]; n1[0] = zf; n1[1] = zf; n1[2] = zf; n1[3] = zf;
      for (int s = 0; s < 4; s++) {
        stageB(wsL + (8 + s) * 2 * SLW);   // entry barrier also covers the A-conversion
        for (int sb = 0; sb < 2; sb++) {
          int ak = (mt * 16 + ml) * NSTR + s * 64 + sb * 32 + q * 8;
          short8 ah = *(const short8*)&sh_Ah[ak];
          short8 al = *(const short8*)&sh_Al[ak];
#pragma unroll
          for (int t = 0; t < 4; t++) {
            int bi = ((nh * 4 + t) * 16 + ml) * BSTR + sb * 32 + q * 8;
            short8 bh = *(const short8*)&sh_B[bi];
            short8 bl = *(const short8*)&sh_B[9216 + bi];
            n1[t] = MFMA_BF16(ah, bh, n1[t], 0, 0, 0);
            n1[t] = MFMA_BF16(ah, bl, n1[t], 0, 0, 0);
            n1[t] = MFMA_BF16(al, bh, n1[t], 0, 0, 0);
          }
        }
      }
      __syncthreads();   // all waves done reading A (NSTR) before in-place ASTR rewrite
#pragma unroll
      for (int t = 0; t < 4; t++) {
        int col = (nh * 4 + t) * 16 + ml;
        float nb1c = sh_tail[768 + col];
#pragma unroll
        for (int r = 0; r < 4; r++) {
          float v = siluf(n1[t][r] + nb1c);
          unsigned short hi, lo; splitbf(v, hi, lo);
          int ai = (mt * 16 + q * 4 + r) * ASTR + col;
          sh_Ah[ai] = hi; sh_Al[ai] = lo;
        }
      }
      f32x4 n2[4]; n2[0] = zf; n2[1] = zf; n2[2] = zf; n2[3] = zf;
      for (int s = 0; s < 2; s++) {
        stageB(wsL + (12 + s) * 2 * SLW);  // entry barrier covers the A2 writes
        for (int sb = 0; sb < 2; sb++) {
          int ak = (mt * 16 + ml) * ASTR + s * 64 + sb * 32 + q * 8;
          short8 ah = *(const short8*)&sh_Ah[ak];
          short8 al = *(const short8*)&sh_Al[ak];
#pragma unroll
          for (int t = 0; t < 4; t++) {
            int bi = ((nh * 4 + t) * 16 + ml) * BSTR + sb * 32 + q * 8;
            short8 bh = *(const short8*)&sh_B[bi];
            short8 bl = *(const short8*)&sh_B[9216 + bi];
            n2[t] = MFMA_BF16(ah, bh, n2[t], 0, 0, 0);
            n2[t] = MFMA_BF16(ah, bl, n2[t], 0, 0, 0);
            n2[t] = MFMA_BF16(al, bh, n2[t], 0, 0, 0);
          }
        }
      }
#pragma unroll
      for (int t = 0; t < 4; t++) {
        int col = (nh * 4 + t) * 16 + ml;
        float nb2c = sh_tail[896 + col];
#pragma unroll
        for (int r = 0; r < 4; r++) {
          int row = mt * 16 + q * 4 + r;
          if (row < NNODE) sh_h[row * HH + col] += n2[t][r] + nb2c;
        }
      }
    }
    __syncthreads();
    // x += xacc; reset accumulators
    for (int idx = tid; idx < NNODE * 3; idx += 256) {
      int n = idx / 3, d = idx % 3;
      sh_x[n][d] += sh_xacc[n][d];
      sh_xacc[n][d] = 0.f;
    }
    for (int idx = tid; idx < NNODE * HH; idx += 256) sh_agg[idx] = 0.f;
    __syncthreads();
  } // layers

  // ---------------- epilogue ----------------
  if (tid < 3) {
    float s = 0.f;
    for (int n = 0; n < NNODE; n++) s += sh_x[n][tid];
    sh_mean[tid] = s * (1.0f / NNODE);
  }
  __syncthreads();
  {
    float tg = sh_scal[1];
    float den = tg * tg + SIG * SIG;
    float c_skip = (SIG * SIG) / den;
    float c_out  = tg * SIG * rsqrtf(den);
    for (int idx = tid; idx < NNODE * 3; idx += 256) {
      int n = idx / 3, d = idx % 3;
      out[(size_t)g * NNODE * 3 + idx] =
          xt[(size_t)g * NNODE * 3 + idx] * c_skip + (sh_x[n][d] - sh_mean[d]) * c_out;
    }
  }
}

extern "C" void kernel_launch(void* const* d_in, const int* in_sizes, int n_in,
                              void* d_out, int out_size, void* d_ws, size_t ws_size,
                              hipStream_t stream) {
  const float* xt         = (const float*)d_in[0];
  const float* t          = (const float*)d_in[1];
  const float* atom_table = (const float*)d_in[2];
  const float* bond_mask  = (const float*)d_in[3];
  const float* W_in       = (const float*)d_in[4];
  const float* b_in       = (const float*)d_in[5];
  const float* ew1        = (const float*)d_in[6];
  const float* eb1        = (const float*)d_in[7];
  const float* ew2        = (const float*)d_in[8];
  const float* eb2        = (const float*)d_in[9];
  const float* aw         = (const float*)d_in[10];
  const float* ab         = (const float*)d_in[11];
  const float* cw1        = (const float*)d_in[12];
  const float* cb1        = (const float*)d_in[13];
  const float* cw2        = (const float*)d_in[14];
  const float* nw1        = (const float*)d_in[15];
  const float* nb1        = (const float*)d_in[16];
  const float* nw2        = (const float*)d_in[17];
  const float* nb2        = (const float*)d_in[18];
  const int* atom_types   = (const int*)d_in[21];

  unsigned short* ws = (unsigned short*)d_ws;   // needs 4*14*2*9216*2 = 2,064,384 B

  prep_weights<<<2016, 256, 0, stream>>>(ew1, ew2, cw1, nw1, nw2, ws);

  scorenet_kernel<<<NB, 256, 0, stream>>>(
      xt, t, atom_table, bond_mask, W_in, b_in,
      ew1, eb1, eb2, aw, ab, cb1, cw2, nb1, nb2,
      atom_types, ws, (float*)d_out);
}

// Round 4
// 751.751 us; speedup vs baseline: 3.3905x; 1.4465x over previous
//
#include <hip/hip_runtime.h>
#include <math.h>

#define NB 512
#define NNODE 22
#define HH 128
#define NEDGE 462
#define NLAYER 4
#define CHUNK2 128
#define NSUP 4
#define SIG 0.168f

#define ASTR 136      // A-plane row stride (ushort), 272B
#define NSTR 264      // A-plane row stride for node concat (K=256), 528B
#define BSTR 72       // B-plane row stride (ushort), 144B
#define SLW (128*72)  // one weight plane in ushorts (= 9216; 18432 B)
#define LSLICES 14    // slices/layer: ew1:0-3, ew2:4-5, cw1:6-7, nw1:8-11, nw2:12-13
#define STAGE_BYTES 36864

typedef __attribute__((ext_vector_type(8))) short short8;
typedef __attribute__((ext_vector_type(4))) short short4v;
typedef __attribute__((ext_vector_type(4))) float f32x4;

#define MFMA_BF16 __builtin_amdgcn_mfma_f32_16x16x32_bf16

__device__ __forceinline__ float siluf(float v) { return v / (1.0f + __expf(-v)); }

__device__ __forceinline__ unsigned short f2bf(float x) {
  union { float f; unsigned u; } v; v.f = x;
  unsigned r = v.u + 0x7FFFu + ((v.u >> 16) & 1u);
  return (unsigned short)(r >> 16);
}
__device__ __forceinline__ float bf2f(unsigned short h) {
  union { unsigned u; float f; } v; v.u = ((unsigned)h) << 16; return v.f;
}
// truncation split: hi = truncate(x) (1 op), lo = round(x - hi); residual exact to ~2^-16 rel
__device__ __forceinline__ void splitbf(float x, unsigned short& hi, unsigned short& lo) {
  union { float f; unsigned u; } v; v.f = x;
  hi = (unsigned short)(v.u >> 16);
  union { unsigned u; float f; } hv; hv.u = ((unsigned)hi) << 16;
  lo = f2bf(x - hv.f);
}

// ---------------- prep: fp32 weights -> (hi,lo) bf16 planes, transposed [n][k] ----------------
__global__ void prep_weights(const float* __restrict__ ew1, const float* __restrict__ ew2,
                             const float* __restrict__ cw1, const float* __restrict__ nw1,
                             const float* __restrict__ nw2, unsigned short* __restrict__ ws)
{
  int idx = blockIdx.x * 256 + threadIdx.x;      // total = 4*14*128*72 = 516096
  if (idx >= 4 * LSLICES * 128 * 72) return;
  int kk = idx % 72; int rest = idx / 72;
  int n = rest % 128; rest /= 128;
  int sl = rest % LSLICES; int l = rest / LSLICES;
  float val = 0.f;
  if (kk < 64) {
    if (sl < 4)       val = ew1[((size_t)l * 259 + sl * 64 + kk) * HH + n];
    else if (sl < 6)  val = ew2[((size_t)l * 128 + (sl - 4) * 64 + kk) * HH + n];
    else if (sl < 8)  val = cw1[((size_t)l * 128 + (sl - 6) * 64 + kk) * HH + n];
    else if (sl < 12) val = nw1[((size_t)l * 256 + (sl - 8) * 64 + kk) * HH + n];
    else              val = nw2[((size_t)l * 128 + (sl - 12) * 64 + kk) * HH + n];
  }
  unsigned short hi, lo; splitbf(val, hi, lo);
  size_t base = ((size_t)(l * LSLICES + sl) * 2) * SLW + n * BSTR + kk;
  ws[base]       = hi;
  ws[base + SLW] = lo;
}

// ---------------- main ----------------
__global__ __launch_bounds__(512, 1)
void scorenet_kernel(
    const float* __restrict__ xt, const float* __restrict__ tt,
    const float* __restrict__ atom_table, const float* __restrict__ bond_mask,
    const float* __restrict__ W_in, const float* __restrict__ b_in,
    const float* __restrict__ ew1, const float* __restrict__ eb1,
    const float* __restrict__ eb2,
    const float* __restrict__ aw,  const float* __restrict__ ab,
    const float* __restrict__ cb1, const float* __restrict__ cw2,
    const float* __restrict__ nb1, const float* __restrict__ nb2,
    const int* __restrict__ atom_types,
    const unsigned short* __restrict__ ws,
    float* __restrict__ out)
{
  const int g    = blockIdx.x;
  const int tid  = threadIdx.x;
  const int lane = tid & 63;
  const int wv   = tid >> 6;          // 0..7
  const int ml   = lane & 15;
  const int q    = lane >> 4;
  const int grp  = wv >> 2;           // edge sub-chunk group (0/1)
  const int ws4  = wv & 3;            // M-tile within sub-chunk
  const int mtn  = wv & 1;            // Phi/node M-tile
  const int nqn  = wv >> 1;           // Phi/node N-quarter (0..3)

  __shared__ unsigned short sh_B[2 * SLW];           // 36864 B
  __shared__ unsigned short sh_Ah[CHUNK2 * ASTR];    // 34816 B
  __shared__ unsigned short sh_Al[CHUNK2 * ASTR];    // 34816 B
  __shared__ float sh_Phi[2][NNODE * HH];            // 22528 B
  __shared__ float sh_h[NNODE * HH];                 // 11264 B
  __shared__ float sh_agg[NNODE * HH];               // 11264 B
  __shared__ float sh_tail[8 * HH];                  // 4096 B
  __shared__ float sh_awl[HH], sh_cw2l[HH];          // 1024 B
  __shared__ float sh_x[NNODE][3], sh_xacc[NNODE][3];
  __shared__ float sh_d0[NEDGE];                     // 1848 B (fp32: precision-critical)
  __shared__ unsigned short sh_bond[NEDGE];          // 924 B (0/1 exact in bf16)
  __shared__ float sh_cd[3][CHUNK2];                 // 1536 B
  __shared__ float sh_cmul[CHUNK2];                  // 512 B
  __shared__ float sh_tf[32], sh_scal[2], sh_mean[3];

  // bare staging issue (no barriers): caller's surrounding barriers sequence it
  auto issueB = [&](const unsigned short* src) {
    const char* s8 = (const char*)src;
    char* dbase = (char*)&sh_B[0];
    for (int base = wv * 1024; base < STAGE_BYTES; base += 8192) {
      __builtin_amdgcn_global_load_lds(
          (const __attribute__((address_space(1))) unsigned int*)(s8 + base + lane * 16),
          (__attribute__((address_space(3))) unsigned int*)(dbase + base),
          16, 0, 0);
    }
  };

  auto gemmE = [&](f32x4 (&acc)[8], int koff) {
    int arow = (grp * 64 + ws4 * 16 + ml) * ASTR + koff;
#pragma unroll
    for (int sb = 0; sb < 2; sb++) {
      int ak = arow + sb * 32 + q * 8;
      short8 ah = *(const short8*)&sh_Ah[ak];
      short8 al = *(const short8*)&sh_Al[ak];
#pragma unroll
      for (int t = 0; t < 8; t++) {
        int bi = (t * 16 + ml) * BSTR + sb * 32 + q * 8;
        short8 bh = *(const short8*)&sh_B[bi];
        short8 bl = *(const short8*)&sh_B[SLW + bi];
        acc[t] = MFMA_BF16(ah, bh, acc[t], 0, 0, 0);
        acc[t] = MFMA_BF16(ah, bl, acc[t], 0, 0, 0);
        acc[t] = MFMA_BF16(al, bh, acc[t], 0, 0, 0);
      }
    }
  };

  auto gemmN = [&](f32x4 (&acc)[2], int astr, int koff) {
#pragma unroll
    for (int sb = 0; sb < 2; sb++) {
      int ak = (mtn * 16 + ml) * astr + koff + sb * 32 + q * 8;
      short8 ah = *(const short8*)&sh_Ah[ak];
      short8 al = *(const short8*)&sh_Al[ak];
#pragma unroll
      for (int tt = 0; tt < 2; tt++) {
        int bi = ((nqn * 2 + tt) * 16 + ml) * BSTR + sb * 32 + q * 8;
        short8 bh = *(const short8*)&sh_B[bi];
        short8 bl = *(const short8*)&sh_B[SLW + bi];
        acc[tt] = MFMA_BF16(ah, bh, acc[tt], 0, 0, 0);
        acc[tt] = MFMA_BF16(ah, bl, acc[tt], 0, 0, 0);
        acc[tt] = MFMA_BF16(al, bh, acc[tt], 0, 0, 0);
      }
    }
  };

  // ---------------- init ----------------
  if (tid == 0) {
    float tg = tt[g];
    sh_scal[0] = rsqrtf(tg * tg + SIG * SIG);
    sh_scal[1] = tg;
  }
  __syncthreads();
  const float c_in = sh_scal[0];
  for (int idx = tid; idx < NNODE * 3; idx += 512) {
    sh_x[idx / 3][idx % 3] = xt[(size_t)g * NNODE * 3 + idx] * c_in;
    sh_xacc[idx / 3][idx % 3] = 0.f;
  }
  if (tid < 32) {
    float u = __logf(sh_scal[1]) * 0.25f;
    int   qq = tid & 15;
    float f = __expf((float)qq * -0.5756462732485115f);
    float a = u * f;
    sh_tf[tid] = (tid < 16) ? __sinf(a) : __cosf(a);
  }
  // zero A planes once (avoid NaN bit-patterns in never-written rows)
  for (int idx = tid; idx < CHUNK2 * ASTR / 2; idx += 512) {
    ((unsigned*)sh_Ah)[idx] = 0u; ((unsigned*)sh_Al)[idx] = 0u;
  }
  __syncthreads();
  // Tvec -> sh_agg row 0, atom-type vecs -> rows 1..4 (scratch)
  for (int o = tid; o < HH; o += 512) {
    float s = b_in[o];
#pragma unroll 8
    for (int k = 0; k < 32; k++) s += sh_tf[k] * W_in[k * HH + o];
    sh_agg[o] = s;
  }
  for (int idx = tid; idx < 4 * HH; idx += 512) {
    int a = idx >> 7, o = idx & 127;
    float s = 0.f;
#pragma unroll 8
    for (int k = 0; k < 32; k++) s += atom_table[a * 32 + k] * W_in[(32 + k) * HH + o];
    sh_agg[(1 + a) * HH + o] = s;
  }
  for (int e = tid; e < NEDGE; e += 512) {
    int i = e / 21; int r = e - i * 21; int jn = r + (r >= i);
    float dx = sh_x[i][0] - sh_x[jn][0];
    float dy = sh_x[i][1] - sh_x[jn][1];
    float dz = sh_x[i][2] - sh_x[jn][2];
    sh_d0[e]   = dx * dx + dy * dy + dz * dz;
    sh_bond[e] = f2bf(bond_mask[(size_t)g * NEDGE + e]);
  }
  __syncthreads();
  for (int idx = tid; idx < NNODE * HH; idx += 512) {
    int n = idx >> 7, o = idx & 127;
    int at = atom_types[n];
    sh_h[idx] = sh_agg[o] + sh_agg[(1 + at) * HH + o];
  }
  issueB(ws);                           // layer 0, slice 0 in flight
  __syncthreads();
  for (int idx = tid; idx < NNODE * HH; idx += 512) sh_agg[idx] = 0.f;

  const f32x4 zf = {0.f, 0.f, 0.f, 0.f};

  // ---------------- layers ----------------
  for (int l = 0; l < NLAYER; l++) {
    const unsigned short* wsL = ws + (size_t)l * LSLICES * 2 * SLW;
    const float abl = ab[l];

    // ---- layer-top phase (overlaps slice-0 load): vectors + h -> ASTR planes ----
    for (int idx = tid; idx < 8 * HH; idx += 512) {
      int rsel = idx >> 7, n = idx & 127;
      float v;
      switch (rsel) {
        case 0: v = ew1[((size_t)l * 259 + 256) * HH + n]; break;
        case 1: v = ew1[((size_t)l * 259 + 257) * HH + n]; break;
        case 2: v = ew1[((size_t)l * 259 + 258) * HH + n]; break;
        case 3: v = eb1[l * HH + n]; break;
        case 4: v = eb2[l * HH + n]; break;
        case 5: v = cb1[l * HH + n]; break;
        case 6: v = nb1[l * HH + n]; break;
        default: v = nb2[l * HH + n]; break;
      }
      sh_tail[idx] = v;
    }
    if (tid < HH) sh_awl[tid] = aw[l * HH + tid];
    else if (tid < 2 * HH) sh_cw2l[tid - HH] = cw2[l * HH + (tid - HH)];
    for (int idx = tid; idx < NNODE * 16; idx += 512) {
      int nd = idx >> 4, nb = (idx & 15) * 8;
      const float* hp = &sh_h[nd * HH + nb];
      union { short8 v; unsigned short s[8]; } oh, ol;
#pragma unroll
      for (int jj = 0; jj < 8; jj++) { unsigned short hi, lo; splitbf(hp[jj], hi, lo); oh.s[jj] = hi; ol.s[jj] = lo; }
      *(short8*)&sh_Ah[nd * ASTR + nb] = oh.v;
      *(short8*)&sh_Al[nd * ASTR + nb] = ol.v;
    }
    __syncthreads();                      // drain slice0; tail/A visible

    // ---- Phi GEMMs ----
    for (int side = 0; side < 2; side++) {
      f32x4 accP[2] = {zf, zf};
      for (int s2 = 0; s2 < 2; s2++) {
        gemmN(accP, ASTR, s2 * 64);
        __syncthreads();                  // done reading sh_B
        int st = side * 2 + s2;
        issueB(wsL + (st < 3 ? (st + 1) : 4) * 2 * SLW);
        if (s2 == 0) __syncthreads();     // drain (exposed)
      }
#pragma unroll
      for (int tt = 0; tt < 2; tt++) {
        int col = (nqn * 2 + tt) * 16 + ml;
#pragma unroll
        for (int r = 0; r < 4; r++) {
          int row = mtn * 16 + q * 4 + r;
          if (row < NNODE) sh_Phi[side][row * HH + col] = accP[tt][r];
        }
      }
      __syncthreads();                    // drain next slice + Phi visible
    }

    // ---- edge super-chunks (128 edges each, two 4-wave groups) ----
    for (int sc = 0; sc < NSUP; sc++) {
      const int e0 = sc * CHUNK2;
      // (A) prologue m1 (inline rad)  [overlaps ew2-s0 load]
      {
        int nb = (tid & 15) * 8, eb_ = tid >> 4;
        for (int j4 = 0; j4 < 4; j4++) {
          int el = eb_ + 32 * j4; int e = e0 + el;
          union { short8 v; unsigned short s[8]; } oh, ol;
          if (e < NEDGE) {
            int i = e / 21; int r0 = e - i * 21; int jn = r0 + (r0 >= i);
            float dx = sh_x[i][0] - sh_x[jn][0];
            float dy = sh_x[i][1] - sh_x[jn][1];
            float dz = sh_x[i][2] - sh_x[jn][2];
            float rad = dx * dx + dy * dy + dz * dz;
            float d0v = sh_d0[e], bnd = bf2f(sh_bond[e]);
            const float* pi = &sh_Phi[0][i * HH + nb];
            const float* pj = &sh_Phi[1][jn * HH + nb];
#pragma unroll
            for (int jj = 0; jj < 8; jj++) {
              float v = pi[jj] + pj[jj] +
                        rad * sh_tail[nb + jj] + d0v * sh_tail[128 + nb + jj] +
                        bnd * sh_tail[256 + nb + jj] + sh_tail[384 + nb + jj];
              unsigned short hi, lo; splitbf(siluf(v), hi, lo);
              oh.s[jj] = hi; ol.s[jj] = lo;
            }
          } else {
#pragma unroll
            for (int jj = 0; jj < 8; jj++) { oh.s[jj] = 0; ol.s[jj] = 0; }
          }
          *(short8*)&sh_Ah[el * ASTR + nb] = oh.v;
          *(short8*)&sh_Al[el * ASTR + nb] = ol.v;
        }
      }
      __syncthreads();                    // (B) drain + m1 visible
      f32x4 acc2[8];
#pragma unroll
      for (int t = 0; t < 8; t++) acc2[t] = zf;
      gemmE(acc2, 0);                     // (C)
      __syncthreads();                    // (D)
      issueB(wsL + 5 * 2 * SLW);          // (E) ew2-s1; geometry overlaps
      if (tid < CHUNK2) {
        int e = e0 + tid;
        if (e < NEDGE) {
          int i = e / 21; int r = e - i * 21; int jn = r + (r >= i);
          float dx = sh_x[i][0] - sh_x[jn][0];
          float dy = sh_x[i][1] - sh_x[jn][1];
          float dz = sh_x[i][2] - sh_x[jn][2];
          float inv = 1.0f / (sqrtf(dx * dx + dy * dy + dz * dz) + 1.0f);
          sh_cd[0][tid] = dx * inv; sh_cd[1][tid] = dy * inv; sh_cd[2][tid] = dz * inv;
        } else {
          sh_cd[0][tid] = 0.f; sh_cd[1][tid] = 0.f; sh_cd[2][tid] = 0.f;
        }
      }
      __syncthreads();                    // (F) drain
      gemmE(acc2, 64);                    // (G)
      __syncthreads();                    // (H)
      issueB(wsL + 6 * 2 * SLW);          // (I) cw1-s0
      // (J) ew2 epilogue: silu + in-register gate + pre-gated m2 write [overlaps]
      {
        float gpr[4] = {0.f, 0.f, 0.f, 0.f};
#pragma unroll
        for (int t = 0; t < 8; t++) {
          int col = t * 16 + ml;
          float eb2c = sh_tail[512 + col], awc = sh_awl[col];
#pragma unroll
          for (int r = 0; r < 4; r++) {
            float v = siluf(acc2[t][r] + eb2c);
            acc2[t][r] = v;
            gpr[r] += v * awc;
          }
        }
#pragma unroll
        for (int m = 1; m < 16; m <<= 1)
#pragma unroll
          for (int r = 0; r < 4; r++) gpr[r] += __shfl_xor(gpr[r], m, 64);
        float gate[4];
#pragma unroll
        for (int r = 0; r < 4; r++) gate[r] = 1.0f / (1.0f + __expf(-(gpr[r] + abl)));
#pragma unroll
        for (int t = 0; t < 8; t++) {
          int col = t * 16 + ml;
#pragma unroll
          for (int r = 0; r < 4; r++) {
            unsigned short hi, lo; splitbf(acc2[t][r] * gate[r], hi, lo);
            int ai = (grp * 64 + ws4 * 16 + q * 4 + r) * ASTR + col;
            sh_Ah[ai] = hi; sh_Al[ai] = lo;
          }
        }
      }
      __syncthreads();                    // (K) drain + m2 visible
      f32x4 acc3[8];
#pragma unroll
      for (int t = 0; t < 8; t++) acc3[t] = zf;
      gemmE(acc3, 0);                     // (L)
      __syncthreads();                    // (M)
      issueB(wsL + 7 * 2 * SLW);          // (N) cw1-s1
      // (O') agg += sum_e m2_gated[e][:]  [overlaps]
      int elast = ((e0 + CHUNK2 < NEDGE) ? e0 + CHUNK2 : NEDGE) - 1;
      int i_lo = e0 / 21, i_hi = elast / 21;
      int nrows = i_hi - i_lo + 1;
      for (int idx = tid; idx < nrows * 32; idx += 512) {
        int i = i_lo + (idx >> 5), fb = (idx & 31) * 4;
        int es = i * 21; if (es < e0) es = e0;
        int ee = i * 21 + 21;
        if (ee > e0 + CHUNK2) ee = e0 + CHUNK2;
        if (ee > NEDGE) ee = NEDGE;
        float* ap = &sh_agg[i * HH + fb];
        float a4[4];
#pragma unroll
        for (int c = 0; c < 4; c++) a4[c] = ap[c];
        for (int e = es; e < ee; e++) {
          union { short4v v; unsigned short s[4]; } uh, ul;
          uh.v = *(const short4v*)&sh_Ah[(e - e0) * ASTR + fb];
          ul.v = *(const short4v*)&sh_Al[(e - e0) * ASTR + fb];
#pragma unroll
          for (int c = 0; c < 4; c++) a4[c] += bf2f(uh.s[c]) + bf2f(ul.s[c]);
        }
#pragma unroll
        for (int c = 0; c < 4; c++) ap[c] = a4[c];
      }
      __syncthreads();                    // (P) drain
      gemmE(acc3, 64);                    // (Q)
      __syncthreads();                    // (R)
      issueB(sc < 3 ? wsL + 4 * 2 * SLW : wsL + 8 * 2 * SLW);  // (S)
      // (T) cw1 epilogue -> cmul [overlaps]
      {
        float cs[4] = {0.f, 0.f, 0.f, 0.f};
#pragma unroll
        for (int t = 0; t < 8; t++) {
          int col = t * 16 + ml;
          float cb1c = sh_tail[640 + col], cwc = sh_cw2l[col];
#pragma unroll
          for (int r = 0; r < 4; r++) cs[r] += siluf(acc3[t][r] + cb1c) * cwc;
        }
#pragma unroll
        for (int m = 1; m < 16; m <<= 1)
#pragma unroll
          for (int r = 0; r < 4; r++) cs[r] += __shfl_xor(cs[r], m, 64);
        if (ml == 0) {
#pragma unroll
          for (int r = 0; r < 4; r++) sh_cmul[grp * 64 + ws4 * 16 + q * 4 + r] = cs[r];
        }
      }
      __syncthreads();                    // (U) cmul visible
      // (V) xacc  [same phase as next prologue start — disjoint arrays]
      for (int idx = tid; idx < nrows * 3; idx += 512) {
        int i = i_lo + idx / 3, d = idx % 3;
        int es = i * 21; if (es < e0) es = e0;
        int ee = i * 21 + 21;
        if (ee > e0 + CHUNK2) ee = e0 + CHUNK2;
        if (ee > NEDGE) ee = NEDGE;
        float s = 0.f;
        for (int e = es; e < ee; e++) s += sh_cd[d][e - e0] * sh_cmul[e - e0];
        sh_xacc[i][d] += s;
      }
    } // super-chunks

    // ---- node MLP ----
    // (W) [h|agg] -> NSTR planes  [overlaps nw1-s0]
    for (int idx = tid; idx < NNODE * 32; idx += 512) {
      int nd = idx >> 5, kb = (idx & 31) * 8;
      const float* src = (kb < 128) ? &sh_h[nd * HH + kb] : &sh_agg[nd * HH + (kb - 128)];
      union { short8 v; unsigned short s[8]; } oh, ol;
#pragma unroll
      for (int jj = 0; jj < 8; jj++) { unsigned short hi, lo; splitbf(src[jj], hi, lo); oh.s[jj] = hi; ol.s[jj] = lo; }
      *(short8*)&sh_Ah[nd * NSTR + kb] = oh.v;
      *(short8*)&sh_Al[nd * NSTR + kb] = ol.v;
    }
    __syncthreads();                      // (X) drain + A visible
    {
      f32x4 n1a[2] = {zf, zf};
      for (int s = 0; s < 4; s++) {
        gemmN(n1a, NSTR, s * 64);
        __syncthreads();
        issueB(wsL + (s < 3 ? (9 + s) : 12) * 2 * SLW);
        if (s < 3) __syncthreads();       // drain (exposed)
      }
      // n1 epilogue -> ASTR rows 0..21 [overlaps nw2-s0]
#pragma unroll
      for (int tt = 0; tt < 2; tt++) {
        int col = (nqn * 2 + tt) * 16 + ml;
        float nb1c = sh_tail[768 + col];
#pragma unroll
        for (int r = 0; r < 4; r++) {
          int row = mtn * 16 + q * 4 + r;
          if (row < NNODE) {
            unsigned short hi, lo; splitbf(siluf(n1a[tt][r] + nb1c), hi, lo);
            sh_Ah[row * ASTR + col] = hi; sh_Al[row * ASTR + col] = lo;
          }
        }
      }
      __syncthreads();                    // (Y) drain + A visible
      f32x4 n2a[2] = {zf, zf};
      gemmN(n2a, ASTR, 0);
      __syncthreads();
      issueB(wsL + 13 * 2 * SLW);
      // x-update + resets [overlaps nw2-s1 load]
      for (int idx = tid; idx < NNODE * 3; idx += 512) {
        int n = idx / 3, d = idx % 3;
        sh_x[n][d] += sh_xacc[n][d];
        sh_xacc[n][d] = 0.f;
      }
      for (int idx = tid; idx < NNODE * HH; idx += 512) sh_agg[idx] = 0.f;
      __syncthreads();                    // drain
      gemmN(n2a, ASTR, 64);
      __syncthreads();
      if (l < 3) issueB(ws + (size_t)(l + 1) * LSLICES * 2 * SLW);  // next layer slice 0
      // n2 epilogue: h += [overlaps]
#pragma unroll
      for (int tt = 0; tt < 2; tt++) {
        int col = (nqn * 2 + tt) * 16 + ml;
        float nb2c = sh_tail[896 + col];
#pragma unroll
        for (int r = 0; r < 4; r++) {
          int row = mtn * 16 + q * 4 + r;
          if (row < NNODE) sh_h[row * HH + col] += n2a[tt][r] + nb2c;
        }
      }
    }
    __syncthreads();                      // layer end: h visible
  } // layers

  // ---------------- epilogue ----------------
  if (tid < 3) {
    float s = 0.f;
    for (int n = 0; n < NNODE; n++) s += sh_x[n][tid];
    sh_mean[tid] = s * (1.0f / NNODE);
  }
  __syncthreads();
  {
    float tg = sh_scal[1];
    float den = tg * tg + SIG * SIG;
    float c_skip = (SIG * SIG) / den;
    float c_out  = tg * SIG * rsqrtf(den);
    for (int idx = tid; idx < NNODE * 3; idx += 512) {
      int n = idx / 3, d = idx % 3;
      out[(size_t)g * NNODE * 3 + idx] =
          xt[(size_t)g * NNODE * 3 + idx] * c_skip + (sh_x[n][d] - sh_mean[d]) * c_out;
    }
  }
}

extern "C" void kernel_launch(void* const* d_in, const int* in_sizes, int n_in,
                              void* d_out, int out_size, void* d_ws, size_t ws_size,
                              hipStream_t stream) {
  const float* xt         = (const float*)d_in[0];
  const float* t          = (const float*)d_in[1];
  const float* atom_table = (const float*)d_in[2];
  const float* bond_mask  = (const float*)d_in[3];
  const float* W_in       = (const float*)d_in[4];
  const float* b_in       = (const float*)d_in[5];
  const float* ew1        = (const float*)d_in[6];
  const float* eb1        = (const float*)d_in[7];
  const float* ew2        = (const float*)d_in[8];
  const float* eb2        = (const float*)d_in[9];
  const float* aw         = (const float*)d_in[10];
  const float* ab         = (const float*)d_in[11];
  const float* cw1        = (const float*)d_in[12];
  const float* cb1        = (const float*)d_in[13];
  const float* cw2        = (const float*)d_in[14];
  const float* nw1        = (const float*)d_in[15];
  const float* nb1        = (const float*)d_in[16];
  const float* nw2        = (const float*)d_in[17];
  const float* nb2        = (const float*)d_in[18];
  const int* atom_types   = (const int*)d_in[21];

  unsigned short* ws = (unsigned short*)d_ws;   // needs 4*14*2*9216*2 = 2,064,384 B

  prep_weights<<<2016, 256, 0, stream>>>(ew1, ew2, cw1, nw1, nw2, ws);

  scorenet_kernel<<<NB, 512, 0, stream>>>(
      xt, t, atom_table, bond_mask, W_in, b_in,
      ew1, eb1, eb2, aw, ab, cb1, cw2, nb1, nb2,
      atom_types, ws, (float*)d_out);
}